// Round 1
// baseline (161.511 us; speedup 1.0000x reference)
//
#include <hip/hip_runtime.h>
#include <hip/hip_bf16.h>
#include <math.h>

// AnomalyAttention: causal MHA forward.
// Q,K,V: [B=4, L=2048, H=8, E=64] fp32; O: [B,L,H,E] fp32.
// O[b,q,h,:] = softmax_j( 0.125 * Q[b,q,h,:].K[b,j,h,:] , j<=q ) @ V[b,j,h,:]

constexpr int Bn = 4, Ln = 2048, Hn = 8, En = 64;
constexpr int QBLK = 64;   // q rows per workgroup (16 per wave)
constexpr int KVBLK = 32;  // kv rows per tile (= MFMA K-dim for PV)

using f32x4  = __attribute__((ext_vector_type(4))) float;
using bf16x8 = __attribute__((ext_vector_type(8))) short;

__device__ inline short f2bf(float f) {
  unsigned u = __builtin_bit_cast(unsigned, f);
  unsigned r = (u + 0x7fffu + ((u >> 16) & 1u)) >> 16;  // RNE
  return (short)(unsigned short)r;
}

__global__ __launch_bounds__(256)
void attn_fwd(const float* __restrict__ Qg, const float* __restrict__ Kg,
              const float* __restrict__ Vg, float* __restrict__ Og) {
  const int qb   = blockIdx.x;       // 0..31 q-block
  const int bh   = blockIdx.y;       // 0..31
  const int b    = bh >> 3;
  const int h    = bh & 7;
  const int tid  = threadIdx.x;
  const int wave = tid >> 6;         // 0..3
  const int lane = tid & 63;
  const int l16  = lane & 15;
  const int lg   = lane >> 4;        // 0..3

  // pads chosen for 16B alignment of b128 reads + <=2-way bank conflicts
  __shared__ __align__(16) short Klds[KVBLK][72];   // [kv][e], row 144B
  __shared__ __align__(16) short Vtld[En][40];      // [d][kv], row 80B
  __shared__ __align__(16) short Plds[4][16][40];   // [wave][q][kv], row 80B

  const size_t base = ((size_t)b * Ln * Hn + (size_t)h) * En;  // (b,*,h,0)
  const int rowstride = Hn * En;  // 512 floats between consecutive seq positions
  const int qrow = qb * QBLK + wave * 16 + l16;

  // ---- Q fragment (B operand of S^T mfma): lane holds Q[qrow][lg*8+j (+32)]
  bf16x8 qf[2];
  {
    const float* qp = Qg + base + (size_t)qrow * rowstride + lg * 8;
#pragma unroll
    for (int hf = 0; hf < 2; ++hf) {
      f32x4 a = *(const f32x4*)(qp + hf * 32);
      f32x4 c = *(const f32x4*)(qp + hf * 32 + 4);
      bf16x8 v;
      v[0]=f2bf(a[0]); v[1]=f2bf(a[1]); v[2]=f2bf(a[2]); v[3]=f2bf(a[3]);
      v[4]=f2bf(c[0]); v[5]=f2bf(c[1]); v[6]=f2bf(c[2]); v[7]=f2bf(c[3]);
      qf[hf] = v;
    }
  }

  f32x4 acc[4];
#pragma unroll
  for (int t = 0; t < 4; ++t) acc[t] = (f32x4){0.f, 0.f, 0.f, 0.f};
  float m = -INFINITY, l = 0.f;

  const int ntiles = qb * 2 + 2;     // tiles with tb <= q_max of this block
  const int skv = tid >> 3;          // 0..31 staging row
  const int se  = (tid & 7) << 3;    // 0..56 staging col (8 floats)

  for (int t = 0; t < ntiles; ++t) {
    const int tb = t * KVBLK;
    __syncthreads();  // protect LDS tiles from previous iteration's readers
    {   // ---- cooperative stage: K tile row-major, V tile transposed
      const float* kp = Kg + base + (size_t)(tb + skv) * rowstride + se;
      f32x4 a = *(const f32x4*)kp;
      f32x4 c = *(const f32x4*)(kp + 4);
      bf16x8 kv;
      kv[0]=f2bf(a[0]); kv[1]=f2bf(a[1]); kv[2]=f2bf(a[2]); kv[3]=f2bf(a[3]);
      kv[4]=f2bf(c[0]); kv[5]=f2bf(c[1]); kv[6]=f2bf(c[2]); kv[7]=f2bf(c[3]);
      *(bf16x8*)&Klds[skv][se] = kv;

      const float* vp = Vg + base + (size_t)(tb + skv) * rowstride + se;
      a = *(const f32x4*)vp;
      c = *(const f32x4*)(vp + 4);
      Vtld[se + 0][skv] = f2bf(a[0]);
      Vtld[se + 1][skv] = f2bf(a[1]);
      Vtld[se + 2][skv] = f2bf(a[2]);
      Vtld[se + 3][skv] = f2bf(a[3]);
      Vtld[se + 4][skv] = f2bf(c[0]);
      Vtld[se + 5][skv] = f2bf(c[1]);
      Vtld[se + 6][skv] = f2bf(c[2]);
      Vtld[se + 7][skv] = f2bf(c[3]);
    }
    __syncthreads();

    // fully-masked tile for this wave? (still participates in barriers)
    if (tb <= qb * QBLK + wave * 16 + 15) {
      // ---- S^T = K . Q^T  (rows kv, cols q). Two 16-kv subtiles, E=64 -> 2 mfma each.
      f32x4 st[2];
#pragma unroll
      for (int sub = 0; sub < 2; ++sub) {
        bf16x8 k0 = *(const bf16x8*)&Klds[sub * 16 + l16][lg * 8];
        bf16x8 k1 = *(const bf16x8*)&Klds[sub * 16 + l16][32 + lg * 8];
        f32x4 s = (f32x4){0.f, 0.f, 0.f, 0.f};
        s = __builtin_amdgcn_mfma_f32_16x16x32_bf16(k0, qf[0], s, 0, 0, 0);
        s = __builtin_amdgcn_mfma_f32_16x16x32_bf16(k1, qf[1], s, 0, 0, 0);
        st[sub] = s;
      }
      // lane holds S^T[kv = tb+sub*16+lg*4+r][q = qrow]
      float tmax = -INFINITY;
#pragma unroll
      for (int sub = 0; sub < 2; ++sub)
#pragma unroll
        for (int r = 0; r < 4; ++r) {
          const int kvg = tb + sub * 16 + lg * 4 + r;
          float s = st[sub][r] * 0.125f;
          if (kvg > qrow) s = -INFINITY;
          st[sub][r] = s;
          tmax = fmaxf(tmax, s);
        }
      tmax = fmaxf(tmax, __shfl_xor(tmax, 16));
      tmax = fmaxf(tmax, __shfl_xor(tmax, 32));
      const float mn = fmaxf(m, tmax);
      const float rs = __expf(m - mn);   // m=-inf,mn finite -> 0; mn==-inf impossible (kv=0 unmasked)
      float tsum = 0.f;
#pragma unroll
      for (int sub = 0; sub < 2; ++sub)
#pragma unroll
        for (int r = 0; r < 4; ++r) {
          const float p = __expf(st[sub][r] - mn);
          st[sub][r] = p;
          tsum += p;
        }
      tsum += __shfl_xor(tsum, 16);
      tsum += __shfl_xor(tsum, 32);
      l = l * rs + tsum;
      m = mn;

      // ---- rescale accumulator (acc rows are q=(lg*4+r); factor lives on lane q)
#pragma unroll
      for (int r = 0; r < 4; ++r) {
        const float f = __shfl(rs, lg * 4 + r);
        acc[0][r] *= f; acc[1][r] *= f; acc[2][r] *= f; acc[3][r] *= f;
      }

      // ---- P^T regs -> P in LDS (A-operand layout for PV)
#pragma unroll
      for (int sub = 0; sub < 2; ++sub) {
        unsigned u0 = (unsigned)(unsigned short)f2bf(st[sub][0]) |
                      ((unsigned)(unsigned short)f2bf(st[sub][1]) << 16);
        unsigned u1 = (unsigned)(unsigned short)f2bf(st[sub][2]) |
                      ((unsigned)(unsigned short)f2bf(st[sub][3]) << 16);
        *(uint2*)&Plds[wave][l16][sub * 16 + lg * 4] = make_uint2(u0, u1);
      }
      // same-wave LDS write->read: DS pipe is in-order per wave; compiler emits lgkmcnt
      bf16x8 pf = *(const bf16x8*)&Plds[wave][l16][lg * 8];

      // ---- O tile: D[q][d] += P[q][kv] V[kv][d], 4 d-subtiles
#pragma unroll
      for (int dt = 0; dt < 4; ++dt) {
        bf16x8 vf = *(const bf16x8*)&Vtld[dt * 16 + l16][lg * 8];
        acc[dt] = __builtin_amdgcn_mfma_f32_16x16x32_bf16(pf, vf, acc[dt], 0, 0, 0);
      }
    }
  }

  // ---- epilogue: lane holds O[q=(lg*4+r)][d=l16+16*dt]; l lives on lane q
#pragma unroll
  for (int r = 0; r < 4; ++r) {
    const float lq  = __shfl(l, lg * 4 + r);
    const float inv = 1.0f / lq;
    const int qg = qb * QBLK + wave * 16 + lg * 4 + r;
    float* op = Og + base + (size_t)qg * rowstride + l16;
    op[0]  = acc[0][r] * inv;
    op[16] = acc[1][r] * inv;
    op[32] = acc[2][r] * inv;
    op[48] = acc[3][r] * inv;
  }
}

extern "C" void kernel_launch(void* const* d_in, const int* in_sizes, int n_in,
                              void* d_out, int out_size, void* d_ws, size_t ws_size,
                              hipStream_t stream) {
  const float* Q = (const float*)d_in[0];
  const float* K = (const float*)d_in[1];
  const float* V = (const float*)d_in[2];
  float* O = (float*)d_out;
  dim3 grid(Ln / QBLK, Bn * Hn);
  dim3 block(256);
  hipLaunchKernelGGL(attn_fwd, grid, block, 0, stream, Q, K, V, O);
}

// Round 4
// 120.184 us; speedup vs baseline: 1.3439x; 1.3439x over previous
//
#include <hip/hip_runtime.h>
#include <hip/hip_bf16.h>
#include <math.h>

// AnomalyAttention: causal MHA forward.
// Q,K,V: [B=4, L=2048, H=8, E=64] fp32; O: [B,L,H,E] fp32.
// O[b,q,h,:] = softmax_j( 0.125 * Q[b,q,h,:].K[b,j,h,:] , j<=q ) @ V[b,j,h,:]

constexpr int Bn = 4, Ln = 2048, Hn = 8, En = 64;
constexpr int QBLK = 64;   // q rows per workgroup (16 per wave)
constexpr int KVBLK = 32;  // kv rows per tile (= MFMA K-dim for PV)

using f32x4  = __attribute__((ext_vector_type(4))) float;
using bf16x8 = __attribute__((ext_vector_type(8))) short;
using u32x4  = __attribute__((ext_vector_type(4))) unsigned int;

// softmax in exp2 domain: z = s * 0.125 * log2(e)
#define SCALE_LOG2E 0.1803368801111204f

__device__ inline short2 cvt2(float a, float b) {
  __hip_bfloat162 h = __float22bfloat162_rn(make_float2(a, b));  // v_cvt_pk_bf16_f32
  return *reinterpret_cast<short2*>(&h);
}

__device__ inline unsigned pack2(float a, float b) {
  short2 s = cvt2(a, b);
  return *reinterpret_cast<unsigned*>(&s);
}

__device__ inline bf16x8 cvt8(f32x4 a, f32x4 b) {
  short2 p0 = cvt2(a[0], a[1]), p1 = cvt2(a[2], a[3]);
  short2 p2 = cvt2(b[0], b[1]), p3 = cvt2(b[2], b[3]);
  bf16x8 v;
  v[0] = p0.x; v[1] = p0.y; v[2] = p1.x; v[3] = p1.y;
  v[4] = p2.x; v[5] = p2.y; v[6] = p3.x; v[7] = p3.y;
  return v;
}

__global__ __launch_bounds__(256)
void attn_fwd(const float* __restrict__ Qg, const float* __restrict__ Kg,
              const float* __restrict__ Vg, float* __restrict__ Og) {
  // LPT: heaviest q-blocks (largest qb) dispatched first -> balanced makespan
  const int wg   = blockIdx.x;
  const int qb   = 31 - (wg >> 5);
  const int bh   = wg & 31;
  const int b    = bh >> 3;
  const int h    = bh & 7;
  const int tid  = threadIdx.x;
  const int lane = tid & 63;
  const int wave = tid >> 6;
  const int l16  = lane & 15;
  const int lg   = lane >> 4;

  __shared__ __align__(16) short Klds[KVBLK][72];  // [kv][e] row-major
  __shared__ __align__(16) short Vtld[En][40];     // [d][kv] transposed

  const size_t base = ((size_t)b * Ln * Hn + (size_t)h) * En;
  const int rowstride = Hn * En;  // 512
  const int qrow = qb * QBLK + wave * 16 + l16;
  const int wqmin = qb * QBLK + wave * 16;
  const int wqmax = wqmin + 15;

  // Q fragment (B operand of S^T mfma): lane holds Q[qrow][lg*8+j (+32)]
  bf16x8 qf[2];
  {
    const float* qp = Qg + base + (size_t)qrow * rowstride + lg * 8;
#pragma unroll
    for (int hf = 0; hf < 2; ++hf)
      qf[hf] = cvt8(*(const f32x4*)(qp + hf * 32), *(const f32x4*)(qp + hf * 32 + 4));
  }

  f32x4 acc[4];
#pragma unroll
  for (int t = 0; t < 4; ++t) acc[t] = (f32x4){0.f, 0.f, 0.f, 0.f};
  float m = -INFINITY, l = 0.f;

  const int ntiles = qb * 2 + 2;
  // K staging: row skv (b128 write)
  const int skv = tid >> 3;          // 0..31
  const int se  = (tid & 7) << 3;    // 0..56
  // V staging: kv = tid&31 so bank varies with kv/2; staggered scalar writes
  const int vkv = tid & 31;
  const int vse = (tid >> 5) << 3;   // 0..56

  for (int t = 0; t < ntiles; ++t) {
    const int tb = t * KVBLK;
    __syncthreads();  // protect LDS from previous iteration's readers
    {  // cooperative stage: K row-major (b128), V transposed (staggered scalar)
      const float* kp = Kg + base + (size_t)(tb + skv) * rowstride + se;
      *(bf16x8*)&Klds[skv][se] = cvt8(*(const f32x4*)kp, *(const f32x4*)(kp + 4));

      const float* vp = Vg + base + (size_t)(tb + vkv) * rowstride + vse;
      bf16x8 vv = cvt8(*(const f32x4*)vp, *(const f32x4*)(vp + 4));
#pragma unroll
      for (int i = 0; i < 8; ++i) {
        const int ii = (i + vkv + (vse >> 3)) & 7;  // stagger -> ~2-way banks
        Vtld[vse + ii][vkv] = vv[ii];
      }
    }
    __syncthreads();

    if (tb <= wqmax) {  // not fully masked for this wave
      // S^T = K . Q^T  (rows kv, cols q)
      f32x4 st[2];
#pragma unroll
      for (int sub = 0; sub < 2; ++sub) {
        bf16x8 k0 = *(const bf16x8*)&Klds[sub * 16 + l16][lg * 8];
        bf16x8 k1 = *(const bf16x8*)&Klds[sub * 16 + l16][32 + lg * 8];
        f32x4 s = (f32x4){0.f, 0.f, 0.f, 0.f};
        s = __builtin_amdgcn_mfma_f32_16x16x32_bf16(k0, qf[0], s, 0, 0, 0);
        s = __builtin_amdgcn_mfma_f32_16x16x32_bf16(k1, qf[1], s, 0, 0, 0);
        st[sub] = s;
      }
      // lane holds S^T[kv = tb+sub*16+lg*4+r][q = qrow]; scale into exp2 domain
      float tmax = -INFINITY;
      if (tb + KVBLK - 1 > wqmin) {  // diagonal tile: apply causal mask
#pragma unroll
        for (int sub = 0; sub < 2; ++sub)
#pragma unroll
          for (int r = 0; r < 4; ++r) {
            const int kvg = tb + sub * 16 + lg * 4 + r;
            float s = st[sub][r] * SCALE_LOG2E;
            if (kvg > qrow) s = -INFINITY;
            st[sub][r] = s;
            tmax = fmaxf(tmax, s);
          }
      } else {  // interior tile: no mask
#pragma unroll
        for (int sub = 0; sub < 2; ++sub)
#pragma unroll
          for (int r = 0; r < 4; ++r) {
            const float s = st[sub][r] * SCALE_LOG2E;
            st[sub][r] = s;
            tmax = fmaxf(tmax, s);
          }
      }
      tmax = fmaxf(tmax, __shfl_xor(tmax, 16));
      tmax = fmaxf(tmax, __shfl_xor(tmax, 32));
      const float mn = fmaxf(m, tmax);
      const float rs = exp2f(m - mn);
      float tsum = 0.f;
#pragma unroll
      for (int sub = 0; sub < 2; ++sub)
#pragma unroll
        for (int r = 0; r < 4; ++r) {
          const float p = exp2f(st[sub][r] - mn);
          st[sub][r] = p;
          tsum += p;
        }
      tsum += __shfl_xor(tsum, 16);
      tsum += __shfl_xor(tsum, 32);
      l = l * rs + tsum;
      m = mn;

      // rescale accumulator (acc rows are q=lg*4+r; factor lives on lane q)
#pragma unroll
      for (int r = 0; r < 4; ++r) {
        const float f = __shfl(rs, lg * 4 + r);
        acc[0][r] *= f; acc[1][r] *= f; acc[2][r] *= f; acc[3][r] *= f;
      }

      // ---- P redistribution fully in-register (no LDS round-trip).
      // Holder lane (l16', lg') has st[s][r] = P[kv=16s+4lg'+r][q-row l16'].
      // PV A-operand needs lane (l16, lg) = P[q-row l16][kv=8lg..8lg+7].
      // 2-stage butterfly verified per-lane against the R1 Plds semantics:
      //   stage 1 (xor 32): lower lanes offer sub1 up, upper offer sub0 down
      //   stage 2 (xor 16): offer what the xor16 partner needs
      {
        unsigned a0 = pack2(st[0][0], st[0][1]);
        unsigned a1 = pack2(st[0][2], st[0][3]);
        unsigned b0 = pack2(st[1][0], st[1][1]);
        unsigned b1 = pack2(st[1][2], st[1][3]);
        const bool up = lg >= 2;
        unsigned t0 = up ? a0 : b0;
        unsigned t1 = up ? a1 : b1;
        t0 = __shfl_xor(t0, 32);   // now: lower holds partner's sub0, upper holds partner's sub1
        t1 = __shfl_xor(t1, 32);
        unsigned z0 = (lg == 1) ? a0 : (lg == 2) ? b0 : t0;
        unsigned z1 = (lg == 1) ? a1 : (lg == 2) ? b1 : t1;
        unsigned r0 = __shfl_xor(z0, 16);
        unsigned r1 = __shfl_xor(z1, 16);
        u32x4 W;
        switch (lg) {
          case 0:  W[0] = a0; W[1] = a1; W[2] = r0; W[3] = r1; break;
          case 1:  W[0] = r0; W[1] = r1; W[2] = t0; W[3] = t1; break;
          case 2:  W[0] = t0; W[1] = t1; W[2] = r0; W[3] = r1; break;
          default: W[0] = r0; W[1] = r1; W[2] = b0; W[3] = b1; break;
        }
        bf16x8 pf = __builtin_bit_cast(bf16x8, W);

        // O tile: D[q][d] += P[q][kv] V[kv][d], 4 d-subtiles (verified R1 layout)
#pragma unroll
        for (int dt = 0; dt < 4; ++dt) {
          bf16x8 vf = *(const bf16x8*)&Vtld[dt * 16 + l16][lg * 8];
          acc[dt] = __builtin_amdgcn_mfma_f32_16x16x32_bf16(pf, vf, acc[dt], 0, 0, 0);
        }
      }
    }
  }

  // epilogue: lane holds O[q=lg*4+r][d=l16+16*dt]; l lives on lane q
#pragma unroll
  for (int r = 0; r < 4; ++r) {
    const float lq  = __shfl(l, lg * 4 + r);
    const float inv = 1.0f / lq;
    const int qg = qb * QBLK + wave * 16 + lg * 4 + r;
    float* op = Og + base + (size_t)qg * rowstride + l16;
    op[0]  = acc[0][r] * inv;
    op[16] = acc[1][r] * inv;
    op[32] = acc[2][r] * inv;
    op[48] = acc[3][r] * inv;
  }
}

extern "C" void kernel_launch(void* const* d_in, const int* in_sizes, int n_in,
                              void* d_out, int out_size, void* d_ws, size_t ws_size,
                              hipStream_t stream) {
  const float* Q = (const float*)d_in[0];
  const float* K = (const float*)d_in[1];
  const float* V = (const float*)d_in[2];
  float* O = (float*)d_out;
  dim3 grid(32 * 32);  // 1D, LPT-ordered decode in-kernel
  dim3 block(256);
  hipLaunchKernelGGL(attn_fwd, grid, block, 0, stream, Q, K, V, O);
}